// Round 2
// baseline (366.460 us; speedup 1.0000x reference)
//
#include <hip/hip_runtime.h>

#define B_ 8
#define H_ 128
#define W_ 128
#define P_ 16384
#define C_ 64
#define NQ (B_*P_)   // 131072 rows

// ---------------- GEMM: Y[N][64] = X[N][64] @ W^T + bias ----------------
__global__ __launch_bounds__(256) void gemm64_kernel(
    const float* __restrict__ X, const float* __restrict__ W,
    const float* __restrict__ bias, float* __restrict__ Y) {
  __shared__ float Ws[64][65];   // Ws[k][c] = W[c][k]
  __shared__ float Xs[64][65];   // Xs[r][k]
  int tid = threadIdx.x;
  int row0 = blockIdx.x * 64;
  for (int i = tid; i < 4096; i += 256) {
    int a = i >> 6, k = i & 63;        // a = W-row / X-tile-row, k = col
    Ws[k][a] = W[i];                   // coalesced read, stride-65 write: conflict-free
    Xs[a][k] = X[(size_t)row0 * 64 + i];
  }
  __syncthreads();
  int ty = tid >> 4, tx = tid & 15;
  int r0 = ty * 4, c0 = tx * 4;
  float acc[4][4];
  {
    float b0 = bias[c0], b1 = bias[c0 + 1], b2 = bias[c0 + 2], b3 = bias[c0 + 3];
#pragma unroll
    for (int i2 = 0; i2 < 4; i2++) {
      acc[i2][0] = b0; acc[i2][1] = b1; acc[i2][2] = b2; acc[i2][3] = b3;
    }
  }
#pragma unroll 8
  for (int k = 0; k < 64; ++k) {
    float w0 = Ws[k][c0], w1 = Ws[k][c0 + 1], w2 = Ws[k][c0 + 2], w3 = Ws[k][c0 + 3];
#pragma unroll
    for (int i2 = 0; i2 < 4; i2++) {
      float xv = Xs[r0 + i2][k];
      acc[i2][0] += xv * w0;
      acc[i2][1] += xv * w1;
      acc[i2][2] += xv * w2;
      acc[i2][3] += xv * w3;
    }
  }
#pragma unroll
  for (int i2 = 0; i2 < 4; i2++) {
    float4 v = make_float4(acc[i2][0], acc[i2][1], acc[i2][2], acc[i2][3]);
    *(float4*)&Y[(size_t)(row0 + r0 + i2) * 64 + c0] = v;
  }
}

// ------------- depthwise 3x3 conv + offset/mask GEMM (54 outs) -------------
__global__ __launch_bounds__(256) void dwom_kernel(
    const float* __restrict__ X, const float* __restrict__ dw_w,
    const float* __restrict__ dw_b, const float* __restrict__ om_w,
    const float* __restrict__ om_b, float* __restrict__ OM) {
  __shared__ float omwT[64][57];  // omwT[k][o] = om_w[o*64+k], o<54
  __shared__ float dwws[576];
  __shared__ float dwbs[64];
  __shared__ float ombs[54];
  __shared__ float dws[4][64];
  int tid = threadIdx.x;
  for (int i = tid; i < 54 * 64; i += 256) {
    int o = i >> 6, k = i & 63;
    omwT[k][o] = om_w[i];
  }
  for (int i = tid; i < 576; i += 256) dwws[i] = dw_w[i];
  if (tid < 64) dwbs[tid] = dw_b[tid];
  if (tid < 54) ombs[tid] = om_b[tid];
  int q0 = blockIdx.x * 4;
  int lp = tid >> 6;
  int c = tid & 63;
  int q = q0 + lp;
  int b = q >> 14;
  int p = q & 16383;
  int h = p >> 7, w = p & 127;
  __syncthreads();
  float acc = dwbs[c];
  const float* xb = X + (size_t)b * (P_ * 64);
#pragma unroll
  for (int t = 0; t < 9; ++t) {
    int dy = t / 3 - 1, dx = t % 3 - 1;
    int hh = h + dy, ww = w + dx;
    if ((unsigned)hh < 128u && (unsigned)ww < 128u)
      acc += xb[(hh * 128 + ww) * 64 + c] * dwws[c * 9 + t];
  }
  dws[lp][c] = acc;
  __syncthreads();
  if (tid < 216) {
    int lp2 = tid / 54;
    int o = tid - lp2 * 54;
    float a = ombs[o];
#pragma unroll
    for (int k = 0; k < 64; ++k) a += dws[lp2][k] * omwT[k][o];
    OM[(size_t)(q0 + lp2) * 54 + o] = a;
  }
}

// ---------------- deformable bilinear gather ----------------
__global__ __launch_bounds__(256) void dcn_kernel(
    const float* __restrict__ val, const float* __restrict__ OM,
    float* __restrict__ core) {
  int i = blockIdx.x * 256 + threadIdx.x;   // i = q*64 + g*32 + d
  int d = i & 31;
  int g = (i >> 5) & 1;
  int q = i >> 6;
  int b = q >> 14;
  int p = q & 16383;
  int h = p >> 7, w = p & 127;
  const float* omg = OM + (size_t)q * 54 + g * 27;
  const float* vb = val + (size_t)b * (P_ * 64) + g * 32 + d;
  float acc = 0.f;
#pragma unroll
  for (int k = 0; k < 9; ++k) {
    float offx = omg[2 * k], offy = omg[2 * k + 1], m = omg[18 + k];
    float ix = (float)w + ((float)(k % 3) - 1.0f + offx) * 2.0f;
    float iy = (float)h + ((float)(k / 3) - 1.0f + offy) * 2.0f;
    float x0f = floorf(ix), y0f = floorf(iy);
    float tx = ix - x0f, ty = iy - y0f;
    int x0 = (int)x0f, y0 = (int)y0f;
    float w00 = (1.f - ty) * (1.f - tx) * m;
    float w01 = (1.f - ty) * tx * m;
    float w10 = ty * (1.f - tx) * m;
    float w11 = ty * tx * m;
    int x1 = x0 + 1, y1 = y0 + 1;
    bool vx0 = (unsigned)x0 < 128u, vx1 = (unsigned)x1 < 128u;
    bool vy0 = (unsigned)y0 < 128u, vy1 = (unsigned)y1 < 128u;
    if (vy0 && vx0) acc += w00 * vb[(y0 * 128 + x0) * 64];
    if (vy0 && vx1) acc += w01 * vb[(y0 * 128 + x1) * 64];
    if (vy1 && vx0) acc += w10 * vb[(y1 * 128 + x0) * 64];
    if (vy1 && vx1) acc += w11 * vb[(y1 * 128 + x1) * 64];
  }
  core[i] = acc;
}

// ---------------- halves-average + BN + ReLU ----------------
__global__ __launch_bounds__(256) void final_kernel(
    const float* __restrict__ proj, const float* __restrict__ bn_g,
    const float* __restrict__ bn_b, const float* __restrict__ bn_m,
    const float* __restrict__ bn_v, float* __restrict__ out) {
  int i = (blockIdx.x * 256 + threadIdx.x) * 4;  // output element index
  int c2 = (i >> 14) & 31;
  int b = i >> 19;
  size_t f1 = (size_t)i + (size_t)b * 524288;
  float4 a = *(const float4*)(proj + f1);
  float4 c = *(const float4*)(proj + f1 + 524288);
  float scale = bn_g[c2] * rsqrtf(bn_v[c2] + 1e-5f);
  float shift = bn_b[c2] - bn_m[c2] * scale;
  float4 z;
  z.x = fmaxf(0.5f * (a.x + c.x) * scale + shift, 0.f);
  z.y = fmaxf(0.5f * (a.y + c.y) * scale + shift, 0.f);
  z.z = fmaxf(0.5f * (a.z + c.z) * scale + shift, 0.f);
  z.w = fmaxf(0.5f * (a.w + c.w) * scale + shift, 0.f);
  *(float4*)(out + i) = z;
}

extern "C" void kernel_launch(void* const* d_in, const int* in_sizes, int n_in,
                              void* d_out, int out_size, void* d_ws, size_t ws_size,
                              hipStream_t stream) {
  const float* x    = (const float*)d_in[0];
  const float* vp_w = (const float*)d_in[1];
  const float* vp_b = (const float*)d_in[2];
  const float* dw_w = (const float*)d_in[3];
  const float* dw_b = (const float*)d_in[4];
  const float* om_w = (const float*)d_in[5];
  const float* om_b = (const float*)d_in[6];
  const float* op_w = (const float*)d_in[7];
  const float* op_b = (const float*)d_in[8];
  const float* bn_g = (const float*)d_in[9];
  const float* bn_b = (const float*)d_in[10];
  const float* bn_m = (const float*)d_in[11];
  const float* bn_v = (const float*)d_in[12];

  float* ws   = (float*)d_ws;
  float* val  = ws;                  // 8388608 floats (32 MB)
  float* core = ws + 8388608;        // 8388608 floats (32 MB)
  float* om   = ws + 16777216;       // 7077888 floats (27 MB)
  float* proj = ws;                  // reuse val region (dead after dcn)

  gemm64_kernel<<<dim3(NQ / 64), dim3(256), 0, stream>>>(x, vp_w, vp_b, val);
  dwom_kernel<<<dim3(NQ / 4), dim3(256), 0, stream>>>(x, dw_w, dw_b, om_w, om_b, om);
  dcn_kernel<<<dim3(NQ * 64 / 256), dim3(256), 0, stream>>>(val, om, core);
  gemm64_kernel<<<dim3(NQ / 64), dim3(256), 0, stream>>>(core, op_w, op_b, proj);
  final_kernel<<<dim3(out_size / 1024), dim3(256), 0, stream>>>(proj, bn_g, bn_b, bn_m, bn_v, (float*)d_out);
}

// Round 3
// 150.090 us; speedup vs baseline: 2.4416x; 2.4416x over previous
//
#include <hip/hip_runtime.h>

#define B_ 8
#define H_ 128
#define W_ 128
#define P_ 16384
#define C_ 64
#define NQ (B_*P_)   // 131072 rows

static __device__ __forceinline__ void fma4s(float4& a, float s, const float4& v) {
  a.x += s * v.x; a.y += s * v.y; a.z += s * v.z; a.w += s * v.w;
}
static __device__ __forceinline__ void fma4e(float4& a, const float4& u, const float4& v) {
  a.x += u.x * v.x; a.y += u.y * v.y; a.z += u.z * v.z; a.w += u.w * v.w;
}

// ---------------- GEMM: Y[N][64] = X[N][64] @ W^T + bias ----------------
__global__ __launch_bounds__(256) void gemm64_kernel(
    const float* __restrict__ X, const float* __restrict__ W,
    const float* __restrict__ bias, float* __restrict__ Y) {
  __shared__ __align__(16) float Ws[64][68];    // Ws[k][c] = W[c][k]
  __shared__ __align__(16) float XsT[64][68];   // XsT[k][r] = X[row0+r][k]
  int tid = threadIdx.x;
  size_t row0 = (size_t)blockIdx.x * 64;
#pragma unroll
  for (int i0 = 0; i0 < 4096; i0 += 1024) {
    int i = i0 + tid * 4;
    int a = i >> 6, k = i & 63;      // a = c (for W) / r (for X), k..k+3 contiguous
    float4 wv = *(const float4*)(W + i);
    Ws[k][a] = wv.x; Ws[k + 1][a] = wv.y; Ws[k + 2][a] = wv.z; Ws[k + 3][a] = wv.w;
    float4 xv = *(const float4*)(X + row0 * 64 + i);
    XsT[k][a] = xv.x; XsT[k + 1][a] = xv.y; XsT[k + 2][a] = xv.z; XsT[k + 3][a] = xv.w;
  }
  __syncthreads();
  int ty = tid >> 4, tx = tid & 15;
  int r0 = ty * 4, c0 = tx * 4;
  float4 b4 = *(const float4*)(bias + c0);
  float4 acc0 = b4, acc1 = b4, acc2 = b4, acc3 = b4;
#pragma unroll 8
  for (int k = 0; k < 64; ++k) {
    float4 wv = *(const float4*)&Ws[k][c0];
    float4 xv = *(const float4*)&XsT[k][r0];
    fma4s(acc0, xv.x, wv);
    fma4s(acc1, xv.y, wv);
    fma4s(acc2, xv.z, wv);
    fma4s(acc3, xv.w, wv);
  }
  float* yb = Y + (row0 + r0) * 64 + c0;
  *(float4*)(yb) = acc0;
  *(float4*)(yb + 64) = acc1;
  *(float4*)(yb + 128) = acc2;
  *(float4*)(yb + 192) = acc3;
}

// ------------- depthwise 3x3 conv + offset/mask GEMM (54 outs), 64 q/block -------------
__global__ __launch_bounds__(256) void dwom_kernel(
    const float* __restrict__ X, const float* __restrict__ dw_w,
    const float* __restrict__ dw_b, const float* __restrict__ om_w,
    const float* __restrict__ om_b, float* __restrict__ OM) {
  __shared__ __align__(16) float dwsT[64][68];  // dwsT[c][lq]
  __shared__ __align__(16) float omwT[64][60];  // omwT[k][o] = om_w[o*64+k]
  __shared__ __align__(16) float dwwT[9][68];   // dwwT[t][c]
  __shared__ __align__(16) float dwbs[64];
  __shared__ __align__(16) float ombs[56];
  int tid = threadIdx.x;
  for (int i = tid; i < 3456; i += 256) omwT[i & 63][i >> 6] = om_w[i];
  for (int i = tid; i < 576; i += 256) dwwT[i % 9][i / 9] = dw_w[i];
  if (tid < 64) dwbs[tid] = dw_b[tid];
  if (tid < 56) ombs[tid] = (tid < 54) ? om_b[tid] : 0.f;
  int q0 = blockIdx.x * 64;
  int b = q0 >> 14;
  int p0 = q0 & 16383;
  int h = p0 >> 7, w0 = p0 & 127;   // w0 in {0,64}; h fixed for the block
  __syncthreads();

  // ---- depthwise: 64 q x 64 c, float4 over c ----
  {
    int cv = tid & 15;       // c chunk
    int lqq = tid >> 4;      // 0..15
    int c0 = cv * 4;
    const float* xb = X + (size_t)b * 1048576;
    float4 wt[9];
#pragma unroll
    for (int t = 0; t < 9; ++t) wt[t] = *(const float4*)&dwwT[t][c0];
    float4 dwb4 = *(const float4*)&dwbs[c0];
#pragma unroll
    for (int it = 0; it < 4; ++it) {
      int lq = lqq + 16 * it;
      int ww = w0 + lq;
      float4 acc = dwb4;
#pragma unroll
      for (int t = 0; t < 9; ++t) {
        int dy = t / 3 - 1, dx = t % 3 - 1;
        int hh = h + dy, wx = ww + dx;
        if ((unsigned)hh < 128u && (unsigned)wx < 128u) {
          float4 v = *(const float4*)(xb + (((size_t)(hh * 128 + wx)) << 6) + c0);
          fma4e(acc, v, wt[t]);
        }
      }
      dwsT[c0][lq] = acc.x; dwsT[c0 + 1][lq] = acc.y;
      dwsT[c0 + 2][lq] = acc.z; dwsT[c0 + 3][lq] = acc.w;
    }
  }
  __syncthreads();

  // ---- GEMM: 64 q x 54 outs (padded to 56) ----
  int ty = tid >> 4, tx = tid & 15;
  int r0 = ty * 4, o0 = tx * 4;
  if (o0 < 54) {
    float4 b4 = *(const float4*)&ombs[o0];
    float4 acc0 = b4, acc1 = b4, acc2 = b4, acc3 = b4;
#pragma unroll 8
    for (int k = 0; k < 64; ++k) {
      float4 ov = *(const float4*)&omwT[k][o0];
      float4 dv = *(const float4*)&dwsT[k][r0];
      fma4s(acc0, dv.x, ov);
      fma4s(acc1, dv.y, ov);
      fma4s(acc2, dv.z, ov);
      fma4s(acc3, dv.w, ov);
    }
    float accs[4][4] = {{acc0.x, acc0.y, acc0.z, acc0.w},
                        {acc1.x, acc1.y, acc1.z, acc1.w},
                        {acc2.x, acc2.y, acc2.z, acc2.w},
                        {acc3.x, acc3.y, acc3.z, acc3.w}};
#pragma unroll
    for (int i2 = 0; i2 < 4; i2++) {
      size_t base = (size_t)(q0 + r0 + i2) * 54 + o0;
#pragma unroll
      for (int j = 0; j < 4; j++)
        if (o0 + j < 54) OM[base + j] = accs[i2][j];
    }
  }
}

// ---------------- deformable bilinear gather: 16 q/block, float4 over d ----------------
__global__ __launch_bounds__(256) void dcn_kernel(
    const float* __restrict__ val, const float* __restrict__ OM,
    float* __restrict__ core) {
  __shared__ __align__(16) float oms[16 * 54];
  int tid = threadIdx.x;
  int q0 = blockIdx.x * 16;
  if (tid < 216)
    ((float4*)oms)[tid] = ((const float4*)(OM + (size_t)q0 * 54))[tid];
  __syncthreads();
  int lq = tid >> 4;
  int g = (tid >> 3) & 1;
  int dv = tid & 7;
  int q = q0 + lq;
  int b = q >> 14;
  int p = q & 16383;
  int h = p >> 7, w = p & 127;
  const float* og = oms + lq * 54 + g * 27;
  const float* vbase = val + (size_t)b * 1048576 + g * 32 + dv * 4;
  float fw = (float)w, fh = (float)h;
  float4 acc = make_float4(0.f, 0.f, 0.f, 0.f);
#pragma unroll
  for (int k = 0; k < 9; ++k) {
    float offx = og[2 * k], offy = og[2 * k + 1], m = og[18 + k];
    float ix = fw + ((float)(k % 3) - 1.0f + offx) * 2.0f;
    float iy = fh + ((float)(k / 3) - 1.0f + offy) * 2.0f;
    float x0f = floorf(ix), y0f = floorf(iy);
    float tx = ix - x0f, ty = iy - y0f;
    int x0 = (int)x0f, y0 = (int)y0f;
    int x1 = x0 + 1, y1 = y0 + 1;
    float w00 = (1.f - ty) * (1.f - tx) * m;
    float w01 = (1.f - ty) * tx * m;
    float w10 = ty * (1.f - tx) * m;
    float w11 = ty * tx * m;
    bool vx0 = (unsigned)x0 < 128u, vx1 = (unsigned)x1 < 128u;
    bool vy0 = (unsigned)y0 < 128u, vy1 = (unsigned)y1 < 128u;
    if (vy0 && vx0) fma4s(acc, w00, *(const float4*)(vbase + (size_t)((y0 * 128 + x0) << 6)));
    if (vy0 && vx1) fma4s(acc, w01, *(const float4*)(vbase + (size_t)((y0 * 128 + x1) << 6)));
    if (vy1 && vx0) fma4s(acc, w10, *(const float4*)(vbase + (size_t)((y1 * 128 + x0) << 6)));
    if (vy1 && vx1) fma4s(acc, w11, *(const float4*)(vbase + (size_t)((y1 * 128 + x1) << 6)));
  }
  ((float4*)core)[(size_t)q * 16 + g * 8 + dv] = acc;
}

// ---------------- halves-average + BN + ReLU ----------------
__global__ __launch_bounds__(256) void final_kernel(
    const float* __restrict__ proj, const float* __restrict__ bn_g,
    const float* __restrict__ bn_b, const float* __restrict__ bn_m,
    const float* __restrict__ bn_v, float* __restrict__ out) {
  int i = (blockIdx.x * 256 + threadIdx.x) * 4;  // output element index
  int c2 = (i >> 14) & 31;
  int b = i >> 19;
  size_t f1 = (size_t)i + (size_t)b * 524288;
  float4 a = *(const float4*)(proj + f1);
  float4 c = *(const float4*)(proj + f1 + 524288);
  float scale = bn_g[c2] * rsqrtf(bn_v[c2] + 1e-5f);
  float shift = bn_b[c2] - bn_m[c2] * scale;
  float4 z;
  z.x = fmaxf(0.5f * (a.x + c.x) * scale + shift, 0.f);
  z.y = fmaxf(0.5f * (a.y + c.y) * scale + shift, 0.f);
  z.z = fmaxf(0.5f * (a.z + c.z) * scale + shift, 0.f);
  z.w = fmaxf(0.5f * (a.w + c.w) * scale + shift, 0.f);
  *(float4*)(out + i) = z;
}

extern "C" void kernel_launch(void* const* d_in, const int* in_sizes, int n_in,
                              void* d_out, int out_size, void* d_ws, size_t ws_size,
                              hipStream_t stream) {
  const float* x    = (const float*)d_in[0];
  const float* vp_w = (const float*)d_in[1];
  const float* vp_b = (const float*)d_in[2];
  const float* dw_w = (const float*)d_in[3];
  const float* dw_b = (const float*)d_in[4];
  const float* om_w = (const float*)d_in[5];
  const float* om_b = (const float*)d_in[6];
  const float* op_w = (const float*)d_in[7];
  const float* op_b = (const float*)d_in[8];
  const float* bn_g = (const float*)d_in[9];
  const float* bn_b = (const float*)d_in[10];
  const float* bn_m = (const float*)d_in[11];
  const float* bn_v = (const float*)d_in[12];

  float* ws   = (float*)d_ws;
  float* val  = ws;                  // 8388608 floats (32 MB)
  float* core = ws + 8388608;        // 8388608 floats (32 MB)
  float* om   = ws + 16777216;       // 7077888 floats (27 MB)
  float* proj = ws;                  // reuse val region (dead after dcn)

  gemm64_kernel<<<dim3(NQ / 64), dim3(256), 0, stream>>>(x, vp_w, vp_b, val);
  dwom_kernel<<<dim3(NQ / 64), dim3(256), 0, stream>>>(x, dw_w, dw_b, om_w, om_b, om);
  dcn_kernel<<<dim3(NQ / 16), dim3(256), 0, stream>>>(val, om, core);
  gemm64_kernel<<<dim3(NQ / 64), dim3(256), 0, stream>>>(core, op_w, op_b, proj);
  final_kernel<<<dim3(out_size / 1024), dim3(256), 0, stream>>>(proj, bn_g, bn_b, bn_m, bn_v, (float*)d_out);
}

// Round 4
// 132.671 us; speedup vs baseline: 2.7622x; 1.1313x over previous
//
#include <hip/hip_runtime.h>

#define B_ 8
#define H_ 128
#define W_ 128
#define P_ 16384
#define C_ 64
#define NQ (B_*P_)   // 131072 rows

static __device__ __forceinline__ void fma4s(float4& a, float s, const float4& v) {
  a.x += s * v.x; a.y += s * v.y; a.z += s * v.z; a.w += s * v.w;
}
static __device__ __forceinline__ void fma4e(float4& a, const float4& u, const float4& v) {
  a.x += u.x * v.x; a.y += u.y * v.y; a.z += u.z * v.z; a.w += u.w * v.w;
}

// ---------------- GEMM: Y[N][64] = X[N][64] @ W^T + bias ----------------
__global__ __launch_bounds__(256) void gemm64_kernel(
    const float* __restrict__ X, const float* __restrict__ W,
    const float* __restrict__ bias, float* __restrict__ Y) {
  __shared__ __align__(16) float Ws[64][68];    // Ws[k][c] = W[c][k]
  __shared__ __align__(16) float XsT[64][68];   // XsT[k][r] = X[row0+r][k]
  int tid = threadIdx.x;
  size_t row0 = (size_t)blockIdx.x * 64;
#pragma unroll
  for (int i0 = 0; i0 < 4096; i0 += 1024) {
    int i = i0 + tid * 4;
    int a = i >> 6, k = i & 63;
    float4 wv = *(const float4*)(W + i);
    Ws[k][a] = wv.x; Ws[k + 1][a] = wv.y; Ws[k + 2][a] = wv.z; Ws[k + 3][a] = wv.w;
    float4 xv = *(const float4*)(X + row0 * 64 + i);
    XsT[k][a] = xv.x; XsT[k + 1][a] = xv.y; XsT[k + 2][a] = xv.z; XsT[k + 3][a] = xv.w;
  }
  __syncthreads();
  int ty = tid >> 4, tx = tid & 15;
  int r0 = ty * 4, c0 = tx * 4;
  float4 b4 = *(const float4*)(bias + c0);
  float4 acc0 = b4, acc1 = b4, acc2 = b4, acc3 = b4;
#pragma unroll 8
  for (int k = 0; k < 64; ++k) {
    float4 wv = *(const float4*)&Ws[k][c0];
    float4 xv = *(const float4*)&XsT[k][r0];
    fma4s(acc0, xv.x, wv);
    fma4s(acc1, xv.y, wv);
    fma4s(acc2, xv.z, wv);
    fma4s(acc3, xv.w, wv);
  }
  float* yb = Y + (row0 + r0) * 64 + c0;
  *(float4*)(yb) = acc0;
  *(float4*)(yb + 64) = acc1;
  *(float4*)(yb + 128) = acc2;
  *(float4*)(yb + 192) = acc3;
}

// ------------- depthwise 3x3 conv + offset/mask GEMM (54 outs), 64 q/block -------------
__global__ __launch_bounds__(256) void dwom_kernel(
    const float* __restrict__ X, const float* __restrict__ dw_w,
    const float* __restrict__ dw_b, const float* __restrict__ om_w,
    const float* __restrict__ om_b, float* __restrict__ OM) {
  __shared__ __align__(16) float dwsT[64][68];  // dwsT[c][lq]
  __shared__ __align__(16) float omwT[64][60];  // omwT[k][o] = om_w[o*64+k]
  __shared__ __align__(16) float dwwT[9][68];   // dwwT[t][c]
  __shared__ __align__(16) float dwbs[64];
  __shared__ __align__(16) float ombs[56];
  int tid = threadIdx.x;
  for (int i = tid; i < 3456; i += 256) omwT[i & 63][i >> 6] = om_w[i];
  for (int i = tid; i < 576; i += 256) dwwT[i % 9][i / 9] = dw_w[i];
  if (tid < 64) dwbs[tid] = dw_b[tid];
  if (tid < 56) ombs[tid] = (tid < 54) ? om_b[tid] : 0.f;
  int q0 = blockIdx.x * 64;
  int b = q0 >> 14;
  int p0 = q0 & 16383;
  int h = p0 >> 7, w0 = p0 & 127;
  __syncthreads();

  {
    int cv = tid & 15;
    int lqq = tid >> 4;
    int c0 = cv * 4;
    const float* xb = X + (size_t)b * 1048576;
    float4 wt[9];
#pragma unroll
    for (int t = 0; t < 9; ++t) wt[t] = *(const float4*)&dwwT[t][c0];
    float4 dwb4 = *(const float4*)&dwbs[c0];
#pragma unroll
    for (int it = 0; it < 4; ++it) {
      int lq = lqq + 16 * it;
      int ww = w0 + lq;
      float4 acc = dwb4;
#pragma unroll
      for (int t = 0; t < 9; ++t) {
        int dy = t / 3 - 1, dx = t % 3 - 1;
        int hh = h + dy, wx = ww + dx;
        if ((unsigned)hh < 128u && (unsigned)wx < 128u) {
          float4 v = *(const float4*)(xb + (((size_t)(hh * 128 + wx)) << 6) + c0);
          fma4e(acc, v, wt[t]);
        }
      }
      dwsT[c0][lq] = acc.x; dwsT[c0 + 1][lq] = acc.y;
      dwsT[c0 + 2][lq] = acc.z; dwsT[c0 + 3][lq] = acc.w;
    }
  }
  __syncthreads();

  int ty = tid >> 4, tx = tid & 15;
  int r0 = ty * 4, o0 = tx * 4;
  if (o0 < 54) {
    float4 b4 = *(const float4*)&ombs[o0];
    float4 acc0 = b4, acc1 = b4, acc2 = b4, acc3 = b4;
#pragma unroll 8
    for (int k = 0; k < 64; ++k) {
      float4 ov = *(const float4*)&omwT[k][o0];
      float4 dv = *(const float4*)&dwsT[k][r0];
      fma4s(acc0, dv.x, ov);
      fma4s(acc1, dv.y, ov);
      fma4s(acc2, dv.z, ov);
      fma4s(acc3, dv.w, ov);
    }
    float accs[4][4] = {{acc0.x, acc0.y, acc0.z, acc0.w},
                        {acc1.x, acc1.y, acc1.z, acc1.w},
                        {acc2.x, acc2.y, acc2.z, acc2.w},
                        {acc3.x, acc3.y, acc3.z, acc3.w}};
#pragma unroll
    for (int i2 = 0; i2 < 4; i2++) {
      size_t base = (size_t)(q0 + r0 + i2) * 54 + o0;
#pragma unroll
      for (int j = 0; j < 4; j++)
        if (o0 + j < 54) OM[base + j] = accs[i2][j];
    }
  }
}

// ---- fused: dcn gather + output GEMM + halves-avg + BN + ReLU ----
// Block handles 32 q rows: {b, p0+0..15} and {b, p0+8192..8207}; these hold
// both halves of every halving pair, so the final write is one contiguous
// 4KB chunk: out[b*524288 + (p0..p0+16)*64 + c].
__global__ __launch_bounds__(256) void dcn_fused_kernel(
    const float* __restrict__ val, const float* __restrict__ OM,
    const float* __restrict__ op_w, const float* __restrict__ op_b,
    const float* __restrict__ bn_g, const float* __restrict__ bn_b,
    const float* __restrict__ bn_m, const float* __restrict__ bn_v,
    float* __restrict__ out) {
  __shared__ __align__(16) float oms[32 * 54];   // 6.9 KB
  __shared__ __align__(16) float cs[32][68];     // 8.7 KB  core rows
  __shared__ __align__(16) float Ws[64][68];     // 17.4 KB op_w^T
  int tid = threadIdx.x;
  int bid = blockIdx.x;
  int b = bid >> 9;
  int p0 = (bid & 511) * 16;
  int q0lo = b * 16384 + p0;

  // stage op_w transposed
#pragma unroll
  for (int i0 = 0; i0 < 4096; i0 += 1024) {
    int i = i0 + tid * 4;
    int c = i >> 6, k = i & 63;
    float4 wv = *(const float4*)(op_w + i);
    Ws[k][c] = wv.x; Ws[k + 1][c] = wv.y; Ws[k + 2][c] = wv.z; Ws[k + 3][c] = wv.w;
  }
  // stage OM rows for both q-groups (16*54 = 864 floats = 216 float4 each)
  if (tid < 216) {
    ((float4*)oms)[tid] = ((const float4*)(OM + (size_t)q0lo * 54))[tid];
    ((float4*)(oms + 864))[tid] = ((const float4*)(OM + (size_t)(q0lo + 8192) * 54))[tid];
  }
  __syncthreads();

  // ---- dcn gather phase: 2 tasks/thread ----
  {
    int lq = tid >> 4;
    int g = (tid >> 3) & 1;
    int dv = tid & 7;
    const float* vbase = val + (size_t)b * 1048576 + g * 32 + dv * 4;
#pragma unroll
    for (int t = 0; t < 2; ++t) {
      int row = t * 16 + lq;
      int p = p0 + t * 8192 + lq;
      int h = p >> 7, w = p & 127;
      const float* og = oms + row * 54 + g * 27;
      float fw = (float)w, fh = (float)h;
      float4 acc = make_float4(0.f, 0.f, 0.f, 0.f);
#pragma unroll
      for (int k = 0; k < 9; ++k) {
        float offx = og[2 * k], offy = og[2 * k + 1], m = og[18 + k];
        float ix = fw + ((float)(k % 3) - 1.0f + offx) * 2.0f;
        float iy = fh + ((float)(k / 3) - 1.0f + offy) * 2.0f;
        float x0f = floorf(ix), y0f = floorf(iy);
        float tx = ix - x0f, ty = iy - y0f;
        int x0 = (int)x0f, y0 = (int)y0f;
        int x1 = x0 + 1, y1 = y0 + 1;
        float vx0 = ((unsigned)x0 < 128u) ? 1.f : 0.f;
        float vx1 = ((unsigned)x1 < 128u) ? 1.f : 0.f;
        float vy0 = ((unsigned)y0 < 128u) ? 1.f : 0.f;
        float vy1 = ((unsigned)y1 < 128u) ? 1.f : 0.f;
        int xc0 = min(max(x0, 0), 127), xc1 = min(max(x1, 0), 127);
        int yc0 = min(max(y0, 0), 127), yc1 = min(max(y1, 0), 127);
        float w00 = (1.f - ty) * (1.f - tx) * m * vy0 * vx0;
        float w01 = (1.f - ty) * tx * m * vy0 * vx1;
        float w10 = ty * (1.f - tx) * m * vy1 * vx0;
        float w11 = ty * tx * m * vy1 * vx1;
        fma4s(acc, w00, *(const float4*)(vbase + (size_t)((yc0 * 128 + xc0) << 6)));
        fma4s(acc, w01, *(const float4*)(vbase + (size_t)((yc0 * 128 + xc1) << 6)));
        fma4s(acc, w10, *(const float4*)(vbase + (size_t)((yc1 * 128 + xc0) << 6)));
        fma4s(acc, w11, *(const float4*)(vbase + (size_t)((yc1 * 128 + xc1) << 6)));
      }
      *(float4*)&cs[row][g * 32 + dv * 4] = acc;
    }
  }
  __syncthreads();

  // ---- output GEMM phase: thread (ty,tx) -> rows {ty, ty+16}, cols c0..c0+3 ----
  int ty = tid >> 4, tx = tid & 15;
  int c0 = tx * 4;
  float4 bias4 = *(const float4*)(op_b + c0);
  float4 accA = bias4, accB = bias4;
#pragma unroll 4
  for (int k0 = 0; k0 < 64; k0 += 4) {
    float4 a4 = *(const float4*)&cs[ty][k0];
    float4 b4 = *(const float4*)&cs[ty + 16][k0];
    float4 w0 = *(const float4*)&Ws[k0][c0];
    float4 w1 = *(const float4*)&Ws[k0 + 1][c0];
    float4 w2 = *(const float4*)&Ws[k0 + 2][c0];
    float4 w3 = *(const float4*)&Ws[k0 + 3][c0];
    fma4s(accA, a4.x, w0); fma4s(accA, a4.y, w1);
    fma4s(accA, a4.z, w2); fma4s(accA, a4.w, w3);
    fma4s(accB, b4.x, w0); fma4s(accB, b4.y, w1);
    fma4s(accB, b4.z, w2); fma4s(accB, b4.w, w3);
  }

  // ---- halving + BN + ReLU; contiguous coalesced write ----
  int f = (p0 + ty) * 64 + c0;           // within-batch flat position (< 524288)
  int c2 = f >> 14;
  float scale = bn_g[c2] * rsqrtf(bn_v[c2] + 1e-5f);
  float shift = bn_b[c2] - bn_m[c2] * scale;
  float4 z;
  z.x = fmaxf(0.5f * (accA.x + accB.x) * scale + shift, 0.f);
  z.y = fmaxf(0.5f * (accA.y + accB.y) * scale + shift, 0.f);
  z.z = fmaxf(0.5f * (accA.z + accB.z) * scale + shift, 0.f);
  z.w = fmaxf(0.5f * (accA.w + accB.w) * scale + shift, 0.f);
  *(float4*)(out + (size_t)b * 524288 + f) = z;
}

extern "C" void kernel_launch(void* const* d_in, const int* in_sizes, int n_in,
                              void* d_out, int out_size, void* d_ws, size_t ws_size,
                              hipStream_t stream) {
  const float* x    = (const float*)d_in[0];
  const float* vp_w = (const float*)d_in[1];
  const float* vp_b = (const float*)d_in[2];
  const float* dw_w = (const float*)d_in[3];
  const float* dw_b = (const float*)d_in[4];
  const float* om_w = (const float*)d_in[5];
  const float* om_b = (const float*)d_in[6];
  const float* op_w = (const float*)d_in[7];
  const float* op_b = (const float*)d_in[8];
  const float* bn_g = (const float*)d_in[9];
  const float* bn_b = (const float*)d_in[10];
  const float* bn_m = (const float*)d_in[11];
  const float* bn_v = (const float*)d_in[12];

  float* ws   = (float*)d_ws;
  float* val  = ws;                  // 8388608 floats (32 MB)
  float* om   = ws + 16777216;       // 7077888 floats (27 MB)

  gemm64_kernel<<<dim3(NQ / 64), dim3(256), 0, stream>>>(x, vp_w, vp_b, val);
  dwom_kernel<<<dim3(NQ / 64), dim3(256), 0, stream>>>(x, dw_w, dw_b, om_w, om_b, om);
  dcn_fused_kernel<<<dim3(4096), dim3(256), 0, stream>>>(
      val, om, op_w, op_b, bn_g, bn_b, bn_m, bn_v, (float*)d_out);
}